// Round 1
// baseline (280.478 us; speedup 1.0000x reference)
//
#include <hip/hip_runtime.h>

#define BATCH 16
#define CCH   256
#define WLEN  4096
#define OCH   256
#define KW    3
#define CK    768      // CCH*KW
#define WT    64       // w-tile per block
#define BK    64       // ck chunk
#define LDK   72       // padded LDS row (bf16 elems): 144 B stride

typedef short bf16x8 __attribute__((ext_vector_type(8)));
typedef float f32x4  __attribute__((ext_vector_type(4)));

__device__ inline short f2bf(float f) {
    union { float f; unsigned u; } v; v.f = f;
    unsigned r = v.u + 0x7FFFu + ((v.u >> 16) & 1u);   // RNE
    return (short)(r >> 16);
}

// Kernel 1: weight fp32 [256][768] -> bf16 same layout in workspace
__global__ void wconv_kernel(const float* __restrict__ w, short* __restrict__ wb) {
    int i = blockIdx.x * 256 + threadIdx.x;   // 768 blocks * 256 = 196608
    wb[i] = f2bf(w[i]);
}

__global__ __launch_bounds__(256)
void deform_mfma_kernel(const float* __restrict__ x,
                        const short* __restrict__ wb,
                        const float* __restrict__ off,
                        const float* __restrict__ msk,
                        const float* __restrict__ bias,
                        float* __restrict__ out) {
    __shared__ short Wl[OCH * LDK];   // [m][ck] bf16, 36864 B
    __shared__ short Sl[WT * LDK];    // [w][ck] bf16,  9216 B
    __shared__ int   pi0[KW * WT], pi1[KW * WT];
    __shared__ float pw0[KW * WT], pw1[KW * WT];

    const int t    = threadIdx.x;
    const int b    = blockIdx.x >> 6;     // 16 batches
    const int wt   = blockIdx.x & 63;     // 64 tiles of 64
    const int lane = t & 63;
    const int lr   = lane & 15;           // m/n within 16x16 tile
    const int lq   = lane >> 4;           // quad
    const int wave = t >> 6;

    // ---- precompute sampling params per (k, w_local) ----
    if (t < KW * WT) {
        int k  = t >> 6;          // t / WT
        int wl = t & 63;          // t % WT
        int wg = wt * WT + wl;
        float p  = (float)(wg - 1 + k) + off[b * (KW * WLEN) + k * WLEN + wg];
        float m  = msk[b * (KW * WLEN) + k * WLEN + wg];
        float pf = floorf(p);
        float w1 = p - pf;
        float w0 = 1.0f - w1;
        int i0 = (int)pf;
        int i1 = i0 + 1;
        bool v0 = (i0 >= 0) & (i0 < WLEN);
        bool v1 = (i1 >= 0) & (i1 < WLEN);
        pi0[t] = min(max(i0, 0), WLEN - 1);
        pi1[t] = min(max(i1, 0), WLEN - 1);
        pw0[t] = v0 ? m * w0 : 0.0f;
        pw1[t] = v1 ? m * w1 : 0.0f;
    }
    __syncthreads();

    f32x4 acc[4][4];
#pragma unroll
    for (int i = 0; i < 4; ++i)
#pragma unroll
        for (int j = 0; j < 4; ++j)
            acc[i][j] = (f32x4){0.f, 0.f, 0.f, 0.f};

    const float* xb = x + (size_t)b * CCH * WLEN;

    for (int kc = 0; kc < CK; kc += BK) {
        // ---- stage weight chunk: Wl[m][0..63] ----
        {
            int cko  = (t & 7) * 8;
            int mrow = t >> 3;           // 0..31
#pragma unroll
            for (int r = 0; r < 8; ++r) {
                int m = mrow + r * 32;
                bf16x8 v = *reinterpret_cast<const bf16x8*>(wb + m * CK + kc + cko);
                *reinterpret_cast<bf16x8*>(&Wl[m * LDK + cko]) = v;
            }
        }
        // ---- stage sampled chunk: Sl[w][0..63] ----
        {
            int wl  = t & 63;
            int ckg = t >> 6;            // 0..3
            short buf[16];
#pragma unroll
            for (int i = 0; i < 16; ++i) {
                int ck = kc + ckg * 16 + i;
                int c  = ck / 3;                 // magic-mul div
                int k  = ck - 3 * c;
                int kwi = k * WT + wl;
                const float* xr = xb + c * WLEN;
                float s = pw0[kwi] * __ldg(xr + pi0[kwi])
                        + pw1[kwi] * __ldg(xr + pi1[kwi]);
                buf[i] = f2bf(s);
            }
            short* dst = &Sl[wl * LDK + ckg * 16];
            reinterpret_cast<bf16x8*>(dst)[0] = *reinterpret_cast<bf16x8*>(&buf[0]);
            reinterpret_cast<bf16x8*>(dst)[1] = *reinterpret_cast<bf16x8*>(&buf[8]);
        }
        __syncthreads();

        // ---- MFMA: wave handles m rows [wave*64, wave*64+64), all 64 n ----
        {
            int mbase = wave * 64;
#pragma unroll
            for (int ks = 0; ks < 2; ++ks) {
                int kk = ks * 32 + lq * 8;
                bf16x8 af[4], bfv[4];
#pragma unroll
                for (int mt = 0; mt < 4; ++mt)
                    af[mt] = *reinterpret_cast<const bf16x8*>(
                        &Wl[(mbase + mt * 16 + lr) * LDK + kk]);
#pragma unroll
                for (int nt = 0; nt < 4; ++nt)
                    bfv[nt] = *reinterpret_cast<const bf16x8*>(
                        &Sl[(nt * 16 + lr) * LDK + kk]);
#pragma unroll
                for (int mt = 0; mt < 4; ++mt)
#pragma unroll
                    for (int nt = 0; nt < 4; ++nt)
                        acc[mt][nt] = __builtin_amdgcn_mfma_f32_16x16x32_bf16(
                            af[mt], bfv[nt], acc[mt][nt], 0, 0, 0);
            }
        }
        __syncthreads();
    }

    // ---- epilogue: D row = lq*4+reg (oc), col = lr (w) ----
    {
        int mbase = wave * 64;
        float* ob = out + (size_t)b * OCH * WLEN + (size_t)wt * WT;
#pragma unroll
        for (int mt = 0; mt < 4; ++mt) {
#pragma unroll
            for (int r = 0; r < 4; ++r) {
                int oc = mbase + mt * 16 + lq * 4 + r;
                float bv = bias[oc];
                float* orow = ob + (size_t)oc * WLEN + lr;
#pragma unroll
                for (int nt = 0; nt < 4; ++nt)
                    orow[nt * 16] = acc[mt][nt][r] + bv;
            }
        }
    }
}

extern "C" void kernel_launch(void* const* d_in, const int* in_sizes, int n_in,
                              void* d_out, int out_size, void* d_ws, size_t ws_size,
                              hipStream_t stream) {
    const float* x    = (const float*)d_in[0];
    const float* w    = (const float*)d_in[1];
    const float* off  = (const float*)d_in[2];
    const float* msk  = (const float*)d_in[3];
    const float* bias = (const float*)d_in[4];
    float* out = (float*)d_out;
    short* wb  = (short*)d_ws;   // 196608 bf16 = 384 KB

    wconv_kernel<<<768, 256, 0, stream>>>(w, wb);
    deform_mfma_kernel<<<BATCH * (WLEN / WT), 256, 0, stream>>>(x, wb, off, msk, bias, out);
}

// Round 2
// 233.234 us; speedup vs baseline: 1.2026x; 1.2026x over previous
//
#include <hip/hip_runtime.h>

#define BATCH 16
#define CCH   256
#define WLEN  4096
#define OCH   256
#define KW    3
#define CK    768      // CCH*KW
#define WT    64       // w-tile for sampling pass / fallback
#define LDK   72       // fallback kernel padded LDS row

typedef short bf16x8 __attribute__((ext_vector_type(8)));
typedef float f32x4  __attribute__((ext_vector_type(4)));

__device__ inline short f2bf(float f) {
    union { float f; unsigned u; } v; v.f = f;
    unsigned r = v.u + 0x7FFFu + ((v.u >> 16) & 1u);   // RNE
    return (short)(r >> 16);
}

__device__ inline void gl_lds16(const void* g, void* l) {
    __builtin_amdgcn_global_load_lds(
        (const __attribute__((address_space(1))) unsigned int*)g,
        (__attribute__((address_space(3))) unsigned int*)l, 16, 0, 0);
}

// ---------------- kernel 1: weight fp32 [256][768] -> bf16 ----------------
__global__ void wconv_kernel(const float* __restrict__ w, short* __restrict__ wb) {
    int i = blockIdx.x * 256 + threadIdx.x;
    wb[i] = f2bf(w[i]);
}

// ---------------- kernel 2: gather+interp -> S^T[b][w][ck] bf16 ----------------
// grid: nb * 128 blocks (2 ck-halves x 64 w-tiles per batch), 256 threads
__global__ __launch_bounds__(256)
void sample_kernel(const float* __restrict__ x,
                   const float* __restrict__ off,
                   const float* __restrict__ msk,
                   short* __restrict__ St, int b0) {
    __shared__ int   pi0[KW * WT], pi1[KW * WT];
    __shared__ float pw0[KW * WT], pw1[KW * WT];

    const int t      = threadIdx.x;
    const int bl     = blockIdx.x >> 7;          // local batch
    const int b      = b0 + bl;
    const int wt     = (blockIdx.x >> 1) & 63;   // w-tile
    const int ckhalf = blockIdx.x & 1;           // ck range half

    if (t < KW * WT) {
        int k  = t >> 6;
        int wl = t & 63;
        int wg = wt * WT + wl;
        float p  = (float)(wg - 1 + k) + off[b * (KW * WLEN) + k * WLEN + wg];
        float m  = msk[b * (KW * WLEN) + k * WLEN + wg];
        float pf = floorf(p);
        float w1 = p - pf;
        float w0 = 1.0f - w1;
        int i0 = (int)pf;
        int i1 = i0 + 1;
        bool v0 = (i0 >= 0) & (i0 < WLEN);
        bool v1 = (i1 >= 0) & (i1 < WLEN);
        pi0[t] = min(max(i0, 0), WLEN - 1);
        pi1[t] = min(max(i1, 0), WLEN - 1);
        pw0[t] = v0 ? m * w0 : 0.0f;
        pw1[t] = v1 ? m * w1 : 0.0f;
    }
    __syncthreads();

    const int wl  = t >> 2;            // 0..63  w within tile
    const int cko = (t & 3) * 16;      // 0,16,32,48
    const float* xb = x + (size_t)b * CCH * WLEN;
    short* srow = St + ((size_t)bl * WLEN + wt * WT + wl) * CK;

    for (int iter = 0; iter < 6; ++iter) {
        int ckb = (ckhalf * 6 + iter) * 64 + cko;
        short buf[16];
#pragma unroll
        for (int i = 0; i < 16; ++i) {
            int ck = ckb + i;
            int c  = ck / 3;
            int k  = ck - 3 * c;
            int kwi = k * WT + wl;
            float s = pw0[kwi] * xb[c * WLEN + pi0[kwi]]
                    + pw1[kwi] * xb[c * WLEN + pi1[kwi]];
            buf[i] = f2bf(s);
        }
        *reinterpret_cast<bf16x8*>(srow + ckb)     = *reinterpret_cast<bf16x8*>(&buf[0]);
        *reinterpret_cast<bf16x8*>(srow + ckb + 8) = *reinterpret_cast<bf16x8*>(&buf[8]);
    }
}

// ---------------- kernel 3: GEMM  out[b] = W[256x768] * S^T[4096x768]^T ----------------
// grid: nb * 64 blocks (2 m-tiles x 32 n-tiles per batch), 256 threads (4 waves)
// XOR swizzle: physical 16B chunk p of LDS row r holds logical chunk p ^ (r&7)
__global__ __launch_bounds__(256)
void gemm_kernel(const short* __restrict__ wb,
                 const short* __restrict__ St,
                 const float* __restrict__ bias,
                 float* __restrict__ out, int b0) {
    __shared__ short Al[128 * 64];   // 16 KB, rows = oc, 64 k each
    __shared__ short Bl[128 * 64];   // 16 KB, rows = w

    const int t    = threadIdx.x;
    const int bl   = blockIdx.x >> 6;
    const int b    = b0 + bl;
    const int mt0  = ((blockIdx.x >> 5) & 1) * 128;
    const int nt0  = (blockIdx.x & 31) * 128;
    const int lane = t & 63;
    const int wv   = t >> 6;
    const int lr   = lane & 15;
    const int lq   = lane >> 4;
    const int mbase = (wv >> 1) * 64;
    const int nbase = (wv & 1) * 64;

    f32x4 acc[4][4];
#pragma unroll
    for (int i = 0; i < 4; ++i)
#pragma unroll
        for (int j = 0; j < 4; ++j)
            acc[i][j] = (f32x4){0.f, 0.f, 0.f, 0.f};

    const short* Ag = wb + (size_t)mt0 * CK;
    const short* Bg = St + ((size_t)bl * WLEN + nt0) * CK;

    // staging: segment s (0..15) covers rows [s*8, s*8+8); lane -> row s*8 + (lane>>3),
    // physical chunk lane&7; fetch logical chunk (lane&7)^(lane>>3)  (since row&7 == lane>>3)
    const int srow    = lane >> 3;
    const int scolswz = ((lane & 7) ^ (lane >> 3)) * 8;

    for (int kc = 0; kc < CK; kc += 64) {
#pragma unroll
        for (int j = 0; j < 4; ++j) {
            int s = wv * 4 + j;
            gl_lds16(Ag + (size_t)(s * 8 + srow) * CK + kc + scolswz, &Al[s * 512]);
            gl_lds16(Bg + (size_t)(s * 8 + srow) * CK + kc + scolswz, &Bl[s * 512]);
        }
        __syncthreads();

#pragma unroll
        for (int ks = 0; ks < 2; ++ks) {
            int kks = ((ks * 4 + lq) ^ (lr & 7)) * 8;   // swizzled element offset
            bf16x8 af[4], bfv[4];
#pragma unroll
            for (int i = 0; i < 4; ++i) {
                af[i]  = *reinterpret_cast<const bf16x8*>(&Al[(mbase + i * 16 + lr) * 64 + kks]);
                bfv[i] = *reinterpret_cast<const bf16x8*>(&Bl[(nbase + i * 16 + lr) * 64 + kks]);
            }
#pragma unroll
            for (int mt = 0; mt < 4; ++mt)
#pragma unroll
                for (int nt = 0; nt < 4; ++nt)
                    acc[mt][nt] = __builtin_amdgcn_mfma_f32_16x16x32_bf16(
                        af[mt], bfv[nt], acc[mt][nt], 0, 0, 0);
        }
        __syncthreads();
    }

    float* ob = out + ((size_t)b * OCH + mt0) * WLEN + nt0;
#pragma unroll
    for (int mt = 0; mt < 4; ++mt) {
#pragma unroll
        for (int r = 0; r < 4; ++r) {
            int row = mbase + mt * 16 + lq * 4 + r;
            float bv = bias[mt0 + row];
            float* orow = ob + (size_t)row * WLEN + nbase + lr;
#pragma unroll
            for (int nt = 0; nt < 4; ++nt)
                orow[nt * 16] = acc[mt][nt][r] + bv;
        }
    }
}

// ---------------- fallback: round-1 fused kernel (if ws too small) ----------------
__global__ __launch_bounds__(256)
void deform_mfma_kernel(const float* __restrict__ x,
                        const short* __restrict__ wb,
                        const float* __restrict__ off,
                        const float* __restrict__ msk,
                        const float* __restrict__ bias,
                        float* __restrict__ out) {
    __shared__ short Wl[OCH * LDK];
    __shared__ short Sl[WT * LDK];
    __shared__ int   pi0[KW * WT], pi1[KW * WT];
    __shared__ float pw0[KW * WT], pw1[KW * WT];

    const int t    = threadIdx.x;
    const int b    = blockIdx.x >> 6;
    const int wt   = blockIdx.x & 63;
    const int lane = t & 63;
    const int lr   = lane & 15;
    const int lq   = lane >> 4;
    const int wave = t >> 6;

    if (t < KW * WT) {
        int k  = t >> 6;
        int wl = t & 63;
        int wg = wt * WT + wl;
        float p  = (float)(wg - 1 + k) + off[b * (KW * WLEN) + k * WLEN + wg];
        float m  = msk[b * (KW * WLEN) + k * WLEN + wg];
        float pf = floorf(p);
        float w1 = p - pf;
        float w0 = 1.0f - w1;
        int i0 = (int)pf;
        int i1 = i0 + 1;
        bool v0 = (i0 >= 0) & (i0 < WLEN);
        bool v1 = (i1 >= 0) & (i1 < WLEN);
        pi0[t] = min(max(i0, 0), WLEN - 1);
        pi1[t] = min(max(i1, 0), WLEN - 1);
        pw0[t] = v0 ? m * w0 : 0.0f;
        pw1[t] = v1 ? m * w1 : 0.0f;
    }
    __syncthreads();

    f32x4 acc[4][4];
#pragma unroll
    for (int i = 0; i < 4; ++i)
#pragma unroll
        for (int j = 0; j < 4; ++j)
            acc[i][j] = (f32x4){0.f, 0.f, 0.f, 0.f};

    const float* xb = x + (size_t)b * CCH * WLEN;

    for (int kc = 0; kc < CK; kc += 64) {
        {
            int cko  = (t & 7) * 8;
            int mrow = t >> 3;
#pragma unroll
            for (int r = 0; r < 8; ++r) {
                int m = mrow + r * 32;
                bf16x8 v = *reinterpret_cast<const bf16x8*>(wb + m * CK + kc + cko);
                *reinterpret_cast<bf16x8*>(&Wl[m * LDK + cko]) = v;
            }
        }
        {
            int wl  = t & 63;
            int ckg = t >> 6;
            short buf[16];
#pragma unroll
            for (int i = 0; i < 16; ++i) {
                int ck = kc + ckg * 16 + i;
                int c  = ck / 3;
                int k  = ck - 3 * c;
                int kwi = k * WT + wl;
                const float* xr = xb + c * WLEN;
                float s = pw0[kwi] * xr[pi0[kwi]] + pw1[kwi] * xr[pi1[kwi]];
                buf[i] = f2bf(s);
            }
            short* dst = &Sl[wl * LDK + ckg * 16];
            reinterpret_cast<bf16x8*>(dst)[0] = *reinterpret_cast<bf16x8*>(&buf[0]);
            reinterpret_cast<bf16x8*>(dst)[1] = *reinterpret_cast<bf16x8*>(&buf[8]);
        }
        __syncthreads();
        {
            int mbase = wave * 64;
#pragma unroll
            for (int ks = 0; ks < 2; ++ks) {
                int kk = ks * 32 + lq * 8;
                bf16x8 af[4], bfv[4];
#pragma unroll
                for (int mt = 0; mt < 4; ++mt)
                    af[mt] = *reinterpret_cast<const bf16x8*>(&Wl[(mbase + mt * 16 + lr) * LDK + kk]);
#pragma unroll
                for (int nt = 0; nt < 4; ++nt)
                    bfv[nt] = *reinterpret_cast<const bf16x8*>(&Sl[(nt * 16 + lr) * LDK + kk]);
#pragma unroll
                for (int mt = 0; mt < 4; ++mt)
#pragma unroll
                    for (int nt = 0; nt < 4; ++nt)
                        acc[mt][nt] = __builtin_amdgcn_mfma_f32_16x16x32_bf16(
                            af[mt], bfv[nt], acc[mt][nt], 0, 0, 0);
            }
        }
        __syncthreads();
    }

    {
        int mbase = wave * 64;
        float* ob = out + (size_t)b * OCH * WLEN + (size_t)wt * WT;
#pragma unroll
        for (int mt = 0; mt < 4; ++mt) {
#pragma unroll
            for (int r = 0; r < 4; ++r) {
                int oc = mbase + mt * 16 + lq * 4 + r;
                float bv = bias[oc];
                float* orow = ob + (size_t)oc * WLEN + lr;
#pragma unroll
                for (int nt = 0; nt < 4; ++nt)
                    orow[nt * 16] = acc[mt][nt][r] + bv;
            }
        }
    }
}

extern "C" void kernel_launch(void* const* d_in, const int* in_sizes, int n_in,
                              void* d_out, int out_size, void* d_ws, size_t ws_size,
                              hipStream_t stream) {
    const float* x    = (const float*)d_in[0];
    const float* w    = (const float*)d_in[1];
    const float* off  = (const float*)d_in[2];
    const float* msk  = (const float*)d_in[3];
    const float* bias = (const float*)d_in[4];
    float* out = (float*)d_out;
    short* wb  = (short*)d_ws;                       // 384 KB

    wconv_kernel<<<768, 256, 0, stream>>>(w, wb);

    const size_t ST_OFF  = 512 * 1024;
    const size_t SBYTES  = (size_t)WLEN * CK * 2;    // 6 MB per batch
    size_t avail = (ws_size > ST_OFF) ? ws_size - ST_OFF : 0;
    int nb = (int)(avail / SBYTES);
    if (nb > BATCH) nb = BATCH;

    if (nb < 1) {
        // workspace too small for two-pass: fused fallback (round-1 kernel)
        deform_mfma_kernel<<<BATCH * (WLEN / WT), 256, 0, stream>>>(x, wb, off, msk, bias, out);
        return;
    }

    short* St = (short*)((char*)d_ws + ST_OFF);
    for (int b0 = 0; b0 < BATCH; b0 += nb) {
        int n = (BATCH - b0 < nb) ? (BATCH - b0) : nb;
        sample_kernel<<<n * 128, 256, 0, stream>>>(x, off, msk, St, b0);
        gemm_kernel<<<n * 64, 256, 0, stream>>>(wb, St, bias, out, b0);
    }
}

// Round 3
// 230.047 us; speedup vs baseline: 1.2192x; 1.0139x over previous
//
#include <hip/hip_runtime.h>

#define BATCH 16
#define CCH   256
#define WLEN  4096
#define OCH   256
#define KW    3
#define CK    768      // CCH*KW
#define WT    64       // w-tile
#define SLD   200      // sample-kernel LDS row stride (bf16 elems), 400 B, 16B-aligned
#define LDK   72       // fallback kernel padded LDS row

typedef short bf16x8 __attribute__((ext_vector_type(8)));
typedef float f32x4  __attribute__((ext_vector_type(4)));

__device__ inline short f2bf(float f) {
    union { float f; unsigned u; } v; v.f = f;
    unsigned r = v.u + 0x7FFFu + ((v.u >> 16) & 1u);   // RNE
    return (short)(r >> 16);
}

__device__ inline void gl_lds16(const void* g, void* l) {
    __builtin_amdgcn_global_load_lds(
        (const __attribute__((address_space(1))) unsigned int*)g,
        (__attribute__((address_space(3))) unsigned int*)l, 16, 0, 0);
}

// ---------------- kernel 1: weight fp32 [256][768] -> bf16 ----------------
__global__ void wconv_kernel(const float* __restrict__ w, short* __restrict__ wb) {
    int i = blockIdx.x * 256 + threadIdx.x;
    wb[i] = f2bf(w[i]);
}

// ---------------- kernel 2: gather+interp -> S^T[b][w][ck] bf16 ----------------
// grid: nb*256 blocks = nb batches x 64 w-tiles x 4 ck-chunks(192 each); 256 thr
// Lanes run along w so gather addresses are near-monotone (~6 lines/wave-load).
__global__ __launch_bounds__(256)
void sample_kernel(const float* __restrict__ x,
                   const float* __restrict__ off,
                   const float* __restrict__ msk,
                   short* __restrict__ St, int b0) {
    __shared__ short Sl[64 * SLD];                 // 25.6 KB transpose buffer
    __shared__ int   pi0[KW * WT], pi1[KW * WT];
    __shared__ float pw0[KW * WT], pw1[KW * WT];

    const int t     = threadIdx.x;
    const int chunk = blockIdx.x & 3;              // ck-chunk (192 ck = 64 c)
    const int wt    = (blockIdx.x >> 2) & 63;      // w-tile
    const int bl    = blockIdx.x >> 8;             // local batch
    const int b     = b0 + bl;
    const int lane  = t & 63;
    const int wv    = t >> 6;

    if (t < KW * WT) {
        int k  = t >> 6;
        int wl = t & 63;
        int wg = wt * WT + wl;
        float p  = (float)(wg - 1 + k) + off[b * (KW * WLEN) + k * WLEN + wg];
        float m  = msk[b * (KW * WLEN) + k * WLEN + wg];
        float pf = floorf(p);
        float w1 = p - pf;
        float w0 = 1.0f - w1;
        int i0 = (int)pf;
        int i1 = i0 + 1;
        bool v0 = (i0 >= 0) & (i0 < WLEN);
        bool v1 = (i1 >= 0) & (i1 < WLEN);
        pi0[t] = min(max(i0, 0), WLEN - 1);
        pi1[t] = min(max(i1, 0), WLEN - 1);
        pw0[t] = v0 ? m * w0 : 0.0f;
        pw1[t] = v1 ? m * w1 : 0.0f;
    }
    __syncthreads();

    // hoist this lane's (w = lane) interp params for all 3 k into registers
    int   ri0[3], ri1[3];
    float rw0[3], rw1[3];
#pragma unroll
    for (int k = 0; k < 3; ++k) {
        ri0[k] = pi0[k * WT + lane];
        ri1[k] = pi1[k * WT + lane];
        rw0[k] = pw0[k * WT + lane];
        rw1[k] = pw1[k * WT + lane];
    }

    const float* xb = x + (size_t)b * CCH * WLEN;
    const int c0 = chunk * 64 + wv * 16;           // wave's base channel

    // ck (global) = chunk*192 + wv*48 + (j*8+i); k = (j*8+i)%3 is compile-time
#pragma unroll
    for (int j = 0; j < 6; ++j) {
        short buf[8];
#pragma unroll
        for (int i = 0; i < 8; ++i) {
            const int q  = j * 8 + i;
            const int k  = q % 3;                  // constant after unroll
            const int dc = q / 3;
            const float* xr = xb + (size_t)(c0 + dc) * WLEN;
            float s = rw0[k] * xr[ri0[k]] + rw1[k] * xr[ri1[k]];
            buf[i] = f2bf(s);
        }
        // row = lane (w), elems [wv*48 + j*8, +8): 16B-aligned, conflict-free b128
        *reinterpret_cast<bf16x8*>(&Sl[lane * SLD + wv * 48 + j * 8]) =
            *reinterpret_cast<bf16x8*>(buf);
    }
    __syncthreads();

    // write out coalesced: thread -> row w = t>>2, quarter q = t&3 (48 elems)
    {
        const int w = t >> 2;
        const int q = t & 3;
        short* dst = St + ((size_t)bl * WLEN + wt * WT + w) * CK + chunk * 192 + q * 48;
        const short* src = &Sl[w * SLD + q * 48];
#pragma unroll
        for (int j = 0; j < 6; ++j)
            *reinterpret_cast<bf16x8*>(dst + j * 8) =
                *reinterpret_cast<const bf16x8*>(src + j * 8);
    }
}

// ---------------- kernel 3: GEMM  out[b] = W[256x768] * S^T[w][ck]^T ----------------
// grid: nb*64 blocks (64 n-tiles of 64 per batch), 256 thr; tile 256m x 64n
// XOR swizzle: physical 16B chunk p of LDS row r holds logical chunk p ^ (r&7)
__global__ __launch_bounds__(256)
void gemm_kernel(const short* __restrict__ wb,
                 const short* __restrict__ St,
                 const float* __restrict__ bias,
                 float* __restrict__ out, int b0) {
    __shared__ short Al[256 * 64];   // 32 KB, rows = oc
    __shared__ short Bl[64 * 64];    //  8 KB, rows = w

    const int t    = threadIdx.x;
    const int bl   = blockIdx.x >> 6;
    const int b    = b0 + bl;
    const int nt0  = (blockIdx.x & 63) * 64;
    const int lane = t & 63;
    const int wv   = t >> 6;
    const int lr   = lane & 15;
    const int lq   = lane >> 4;
    const int mbase = wv * 64;

    f32x4 acc[4][4];
#pragma unroll
    for (int i = 0; i < 4; ++i)
#pragma unroll
        for (int j = 0; j < 4; ++j)
            acc[i][j] = (f32x4){0.f, 0.f, 0.f, 0.f};

    const short* Ag = wb;                                   // full 256 rows
    const short* Bg = St + ((size_t)bl * WLEN + nt0) * CK;  // 64 rows

    // staging: segment s covers rows [s*8, s*8+8); lane -> row s*8 + (lane>>3),
    // physical chunk lane&7 <- logical chunk (lane&7)^(lane>>3)
    const int srow    = lane >> 3;
    const int scolswz = ((lane & 7) ^ (lane >> 3)) * 8;

    for (int kc = 0; kc < CK; kc += 64) {
#pragma unroll
        for (int j = 0; j < 8; ++j) {               // A: 32 segments
            int s = wv * 8 + j;
            gl_lds16(Ag + (size_t)(s * 8 + srow) * CK + kc + scolswz, &Al[s * 512]);
        }
#pragma unroll
        for (int j = 0; j < 2; ++j) {               // B: 8 segments
            int s = wv * 2 + j;
            gl_lds16(Bg + (size_t)(s * 8 + srow) * CK + kc + scolswz, &Bl[s * 512]);
        }
        __syncthreads();

#pragma unroll
        for (int ks = 0; ks < 2; ++ks) {
            int kks = ((ks * 4 + lq) ^ (lr & 7)) * 8;   // swizzled element offset
            bf16x8 af[4], bfv[4];
#pragma unroll
            for (int i = 0; i < 4; ++i) {
                af[i]  = *reinterpret_cast<const bf16x8*>(&Al[(mbase + i * 16 + lr) * 64 + kks]);
                bfv[i] = *reinterpret_cast<const bf16x8*>(&Bl[(i * 16 + lr) * 64 + kks]);
            }
#pragma unroll
            for (int mt = 0; mt < 4; ++mt)
#pragma unroll
                for (int nt = 0; nt < 4; ++nt)
                    acc[mt][nt] = __builtin_amdgcn_mfma_f32_16x16x32_bf16(
                        af[mt], bfv[nt], acc[mt][nt], 0, 0, 0);
        }
        __syncthreads();
    }

    float* ob = out + (size_t)b * OCH * WLEN + nt0;
#pragma unroll
    for (int mt = 0; mt < 4; ++mt) {
#pragma unroll
        for (int r = 0; r < 4; ++r) {
            int row = mbase + mt * 16 + lq * 4 + r;
            float bv = bias[row];
            float* orow = ob + (size_t)row * WLEN + lr;
#pragma unroll
            for (int nt = 0; nt < 4; ++nt)
                orow[nt * 16] = acc[mt][nt][r] + bv;
        }
    }
}

// ---------------- fallback: fused kernel (if ws too small) ----------------
__global__ __launch_bounds__(256)
void deform_mfma_kernel(const float* __restrict__ x,
                        const short* __restrict__ wb,
                        const float* __restrict__ off,
                        const float* __restrict__ msk,
                        const float* __restrict__ bias,
                        float* __restrict__ out) {
    __shared__ short Wl[OCH * LDK];
    __shared__ short Sl[WT * LDK];
    __shared__ int   pi0[KW * WT], pi1[KW * WT];
    __shared__ float pw0[KW * WT], pw1[KW * WT];

    const int t    = threadIdx.x;
    const int b    = blockIdx.x >> 6;
    const int wt   = blockIdx.x & 63;
    const int lane = t & 63;
    const int lr   = lane & 15;
    const int lq   = lane >> 4;
    const int wave = t >> 6;

    if (t < KW * WT) {
        int k  = t >> 6;
        int wl = t & 63;
        int wg = wt * WT + wl;
        float p  = (float)(wg - 1 + k) + off[b * (KW * WLEN) + k * WLEN + wg];
        float m  = msk[b * (KW * WLEN) + k * WLEN + wg];
        float pf = floorf(p);
        float w1 = p - pf;
        float w0 = 1.0f - w1;
        int i0 = (int)pf;
        int i1 = i0 + 1;
        bool v0 = (i0 >= 0) & (i0 < WLEN);
        bool v1 = (i1 >= 0) & (i1 < WLEN);
        pi0[t] = min(max(i0, 0), WLEN - 1);
        pi1[t] = min(max(i1, 0), WLEN - 1);
        pw0[t] = v0 ? m * w0 : 0.0f;
        pw1[t] = v1 ? m * w1 : 0.0f;
    }
    __syncthreads();

    f32x4 acc[4][4];
#pragma unroll
    for (int i = 0; i < 4; ++i)
#pragma unroll
        for (int j = 0; j < 4; ++j)
            acc[i][j] = (f32x4){0.f, 0.f, 0.f, 0.f};

    const float* xb = x + (size_t)b * CCH * WLEN;

    for (int kc = 0; kc < CK; kc += 64) {
        {
            int cko  = (t & 7) * 8;
            int mrow = t >> 3;
#pragma unroll
            for (int r = 0; r < 8; ++r) {
                int m = mrow + r * 32;
                bf16x8 v = *reinterpret_cast<const bf16x8*>(wb + m * CK + kc + cko);
                *reinterpret_cast<bf16x8*>(&Wl[m * LDK + cko]) = v;
            }
        }
        {
            int wl  = t & 63;
            int ckg = t >> 6;
            short buf[16];
#pragma unroll
            for (int i = 0; i < 16; ++i) {
                int ck = kc + ckg * 16 + i;
                int c  = ck / 3;
                int k  = ck - 3 * c;
                int kwi = k * WT + wl;
                const float* xr = xb + c * WLEN;
                float s = pw0[kwi] * xr[pi0[kwi]] + pw1[kwi] * xr[pi1[kwi]];
                buf[i] = f2bf(s);
            }
            short* dst = &Sl[wl * LDK + ckg * 16];
            reinterpret_cast<bf16x8*>(dst)[0] = *reinterpret_cast<bf16x8*>(&buf[0]);
            reinterpret_cast<bf16x8*>(dst)[1] = *reinterpret_cast<bf16x8*>(&buf[8]);
        }
        __syncthreads();
        {
            int mbase = wave * 64;
#pragma unroll
            for (int ks = 0; ks < 2; ++ks) {
                int kk = ks * 32 + lq * 8;
                bf16x8 af[4], bfv[4];
#pragma unroll
                for (int mt = 0; mt < 4; ++mt)
                    af[mt] = *reinterpret_cast<const bf16x8*>(&Wl[(mbase + mt * 16 + lr) * LDK + kk]);
#pragma unroll
                for (int nt = 0; nt < 4; ++nt)
                    bfv[nt] = *reinterpret_cast<const bf16x8*>(&Sl[(nt * 16 + lr) * LDK + kk]);
#pragma unroll
                for (int mt = 0; mt < 4; ++mt)
#pragma unroll
                    for (int nt = 0; nt < 4; ++nt)
                        acc[mt][nt] = __builtin_amdgcn_mfma_f32_16x16x32_bf16(
                            af[mt], bfv[nt], acc[mt][nt], 0, 0, 0);
            }
        }
        __syncthreads();
    }

    {
        int mbase = wave * 64;
        float* ob = out + (size_t)b * OCH * WLEN + (size_t)wt * WT;
#pragma unroll
        for (int mt = 0; mt < 4; ++mt) {
#pragma unroll
            for (int r = 0; r < 4; ++r) {
                int oc = mbase + mt * 16 + lq * 4 + r;
                float bv = bias[oc];
                float* orow = ob + (size_t)oc * WLEN + lr;
#pragma unroll
                for (int nt = 0; nt < 4; ++nt)
                    orow[nt * 16] = acc[mt][nt][r] + bv;
            }
        }
    }
}

extern "C" void kernel_launch(void* const* d_in, const int* in_sizes, int n_in,
                              void* d_out, int out_size, void* d_ws, size_t ws_size,
                              hipStream_t stream) {
    const float* x    = (const float*)d_in[0];
    const float* w    = (const float*)d_in[1];
    const float* off  = (const float*)d_in[2];
    const float* msk  = (const float*)d_in[3];
    const float* bias = (const float*)d_in[4];
    float* out = (float*)d_out;
    short* wb  = (short*)d_ws;                       // 384 KB

    wconv_kernel<<<768, 256, 0, stream>>>(w, wb);

    const size_t ST_OFF  = 512 * 1024;
    const size_t SBYTES  = (size_t)WLEN * CK * 2;    // 6 MB per batch
    size_t avail = (ws_size > ST_OFF) ? ws_size - ST_OFF : 0;
    int nb = (int)(avail / SBYTES);
    if (nb > BATCH) nb = BATCH;

    if (nb < 1) {
        deform_mfma_kernel<<<BATCH * (WLEN / WT), 256, 0, stream>>>(x, wb, off, msk, bias, out);
        return;
    }

    short* St = (short*)((char*)d_ws + ST_OFF);
    for (int b0 = 0; b0 < BATCH; b0 += nb) {
        int n = (BATCH - b0 < nb) ? (BATCH - b0) : nb;
        sample_kernel<<<n * 256, 256, 0, stream>>>(x, off, msk, St, b0);
        gemm_kernel<<<n * 64, 256, 0, stream>>>(wb, St, bias, out, b0);
    }
}

// Round 4
// 189.116 us; speedup vs baseline: 1.4831x; 1.2164x over previous
//
#include <hip/hip_runtime.h>

#define BATCH 16
#define CCH   256
#define WLEN  4096
#define OCH   256
#define KW    3
#define CK    768      // CCH*KW
#define WT    64       // w-tile
#define SLD   200      // transpose buffer row stride (shorts)
#define WIN   96       // x-window floats per channel (covers offset in ±15)
#define LDK   72       // fallback kernel padded LDS row

typedef short bf16x8 __attribute__((ext_vector_type(8)));
typedef float f32x4  __attribute__((ext_vector_type(4)));

__device__ inline short f2bf(float f) {
    union { float f; unsigned u; } v; v.f = f;
    unsigned r = v.u + 0x7FFFu + ((v.u >> 16) & 1u);   // RNE
    return (short)(r >> 16);
}

__device__ inline void gl_lds16(const void* g, void* l) {
    __builtin_amdgcn_global_load_lds(
        (const __attribute__((address_space(1))) unsigned int*)g,
        (__attribute__((address_space(3))) unsigned int*)l, 16, 0, 0);
}

// ---------------- weight fp32 [256][768] -> bf16 (fallback path only) ----------------
__global__ void wconv_kernel(const float* __restrict__ w, short* __restrict__ wb) {
    int i = blockIdx.x * 256 + threadIdx.x;
    wb[i] = f2bf(w[i]);
}

// ---------------- kernel 2: LDS-window gather+interp -> S^T[b][w][ck] bf16 ----------
// grid: nb*256 blocks = nb batches x 64 w-tiles x 4 ck-chunks(192 ck = 64 ch); 256 thr
// Wave stages 16 channels' 96-float windows coalesced into LDS, then gathers via
// ds_read_b32 (cheap) instead of divergent global loads (expensive TA replays).
__global__ __launch_bounds__(256)
void sample_kernel(const float* __restrict__ x,
                   const float* __restrict__ wsrc,
                   short* __restrict__ wb,
                   const float* __restrict__ off,
                   const float* __restrict__ msk,
                   short* __restrict__ St, int b0) {
    __shared__ float Win_s[4 * 16 * WIN];   // 24576 B
    __shared__ short Sl[64 * SLD];          // 25600 B

    const int t      = threadIdx.x;
    const int chunk  = blockIdx.x & 3;
    const int wt     = (blockIdx.x >> 2) & 63;
    const int bl     = blockIdx.x >> 8;
    const int b      = b0 + bl;
    const int lane   = t & 63;
    const int wv     = t >> 6;
    const int wstart = wt * WT - 16;

    // fold weight conversion into the first sample pass (saves a launch)
    if (b0 == 0) {
        for (int i = blockIdx.x * 256 + t; i < OCH * CK; i += gridDim.x * 256)
            wb[i] = f2bf(wsrc[i]);
    }

    // ---- per-lane sampling params, all in registers (w = wt*64 + lane) ----
    const int wg = wt * WT + lane;
    int   ri0[3], ri1[3];
    float rw0[3], rw1[3];
#pragma unroll
    for (int k = 0; k < 3; ++k) {
        float o  = off[b * (KW * WLEN) + k * WLEN + wg];
        float m  = msk[b * (KW * WLEN) + k * WLEN + wg];
        float p  = (float)(wg - 1 + k) + o;
        float pf = floorf(p);
        float w1 = p - pf;
        int i0 = (int)pf;
        int i1 = i0 + 1;
        bool v0 = (i0 >= 0) & (i0 < WLEN);
        bool v1 = (i1 >= 0) & (i1 < WLEN);
        int l0 = min(max(i0, 0), WLEN - 1) - wstart;
        int l1 = min(max(i1, 0), WLEN - 1) - wstart;
        ri0[k] = min(max(l0, 0), WIN - 1);   // window-local, memory-safe
        ri1[k] = min(max(l1, 0), WIN - 1);
        rw0[k] = v0 ? m * (1.0f - w1) : 0.0f;
        rw1[k] = v1 ? m * w1 : 0.0f;
    }

    // ---- stage x windows: wave's 16 channels x 96 floats, coalesced 16B DMA ----
    const int c0 = chunk * 64 + wv * 16;
    const float* xb = x + (size_t)b * CCH * WLEN;
    {
        float* wbase = &Win_s[wv * 16 * WIN];
#pragma unroll
        for (int it = 0; it < 6; ++it) {
            int i   = it * 64 + lane;
            int ch  = i / 24;               // 24 float4 per channel row
            int o16 = i - ch * 24;
            int j0  = wstart + o16 * 4;
            j0 = min(max(j0, 0), WLEN - 4); // edge tiles: clamp (data unused there)
            // LDS linear float offset i*4 == ch*96 + o16*4 (contiguous layout)
            gl_lds16(xb + (size_t)(c0 + ch) * WLEN + j0, wbase + it * 256);
        }
    }
    __syncthreads();

    // ---- gather from LDS: 16 ch x 3 k x 2 taps = 96 ds_read_b32 per lane ----
    short buf[48];
    {
        const float* wbase = &Win_s[wv * 16 * WIN];
#pragma unroll
        for (int dc = 0; dc < 16; ++dc) {
            const float* row = wbase + dc * WIN;
#pragma unroll
            for (int k = 0; k < 3; ++k) {
                float s = rw0[k] * row[ri0[k]] + rw1[k] * row[ri1[k]];
                buf[dc * 3 + k] = f2bf(s);
            }
        }
    }

    // ---- transpose via LDS, then coalesced store of S^T ----
#pragma unroll
    for (int j = 0; j < 6; ++j)
        *reinterpret_cast<bf16x8*>(&Sl[lane * SLD + wv * 48 + j * 8]) =
            *reinterpret_cast<bf16x8*>(&buf[j * 8]);
    __syncthreads();

    {
        const int w = t >> 2;
        const int q = t & 3;
        short* dst = St + ((size_t)bl * WLEN + wt * WT + w) * CK + chunk * 192 + q * 48;
        const short* src = &Sl[w * SLD + q * 48];
#pragma unroll
        for (int j = 0; j < 6; ++j)
            *reinterpret_cast<bf16x8*>(dst + j * 8) =
                *reinterpret_cast<const bf16x8*>(src + j * 8);
    }
}

// ---------------- kernel 3: GEMM  out[b] = W[256x768] * S^T[w][ck]^T ----------------
// grid: nb*64 blocks (64 n-tiles of 64 per batch), 256 thr; tile 256m x 64n
// XOR swizzle: physical 16B chunk p of LDS row r holds logical chunk p ^ (r&7)
__global__ __launch_bounds__(256)
void gemm_kernel(const short* __restrict__ wb,
                 const short* __restrict__ St,
                 const float* __restrict__ bias,
                 float* __restrict__ out, int b0) {
    __shared__ short Al[256 * 64];   // 32 KB, rows = oc
    __shared__ short Bl[64 * 64];    //  8 KB, rows = w

    const int t    = threadIdx.x;
    const int bl   = blockIdx.x >> 6;
    const int b    = b0 + bl;
    const int nt0  = (blockIdx.x & 63) * 64;
    const int lane = t & 63;
    const int wv   = t >> 6;
    const int lr   = lane & 15;
    const int lq   = lane >> 4;
    const int mbase = wv * 64;

    f32x4 acc[4][4];
#pragma unroll
    for (int i = 0; i < 4; ++i)
#pragma unroll
        for (int j = 0; j < 4; ++j)
            acc[i][j] = (f32x4){0.f, 0.f, 0.f, 0.f};

    const short* Ag = wb;
    const short* Bg = St + ((size_t)bl * WLEN + nt0) * CK;

    const int srow    = lane >> 3;
    const int scolswz = ((lane & 7) ^ (lane >> 3)) * 8;

    for (int kc = 0; kc < CK; kc += 64) {
#pragma unroll
        for (int j = 0; j < 8; ++j) {               // A: 32 segments
            int s = wv * 8 + j;
            gl_lds16(Ag + (size_t)(s * 8 + srow) * CK + kc + scolswz, &Al[s * 512]);
        }
#pragma unroll
        for (int j = 0; j < 2; ++j) {               // B: 8 segments
            int s = wv * 2 + j;
            gl_lds16(Bg + (size_t)(s * 8 + srow) * CK + kc + scolswz, &Bl[s * 512]);
        }
        __syncthreads();

#pragma unroll
        for (int ks = 0; ks < 2; ++ks) {
            int kks = ((ks * 4 + lq) ^ (lr & 7)) * 8;
            bf16x8 af[4], bfv[4];
#pragma unroll
            for (int i = 0; i < 4; ++i) {
                af[i]  = *reinterpret_cast<const bf16x8*>(&Al[(mbase + i * 16 + lr) * 64 + kks]);
                bfv[i] = *reinterpret_cast<const bf16x8*>(&Bl[(i * 16 + lr) * 64 + kks]);
            }
#pragma unroll
            for (int mt = 0; mt < 4; ++mt)
#pragma unroll
                for (int nt = 0; nt < 4; ++nt)
                    acc[mt][nt] = __builtin_amdgcn_mfma_f32_16x16x32_bf16(
                        af[mt], bfv[nt], acc[mt][nt], 0, 0, 0);
        }
        __syncthreads();
    }

    float* ob = out + (size_t)b * OCH * WLEN + nt0;
#pragma unroll
    for (int mt = 0; mt < 4; ++mt) {
#pragma unroll
        for (int r = 0; r < 4; ++r) {
            int row = mbase + mt * 16 + lq * 4 + r;
            float bv = bias[row];
            float* orow = ob + (size_t)row * WLEN + lr;
#pragma unroll
            for (int nt = 0; nt < 4; ++nt)
                orow[nt * 16] = acc[mt][nt][r] + bv;
        }
    }
}

// ---------------- fallback: fused kernel (if ws too small) ----------------
__global__ __launch_bounds__(256)
void deform_mfma_kernel(const float* __restrict__ x,
                        const short* __restrict__ wb,
                        const float* __restrict__ off,
                        const float* __restrict__ msk,
                        const float* __restrict__ bias,
                        float* __restrict__ out) {
    __shared__ short Wl[OCH * LDK];
    __shared__ short Sl[WT * LDK];
    __shared__ int   pi0[KW * WT], pi1[KW * WT];
    __shared__ float pw0[KW * WT], pw1[KW * WT];

    const int t    = threadIdx.x;
    const int b    = blockIdx.x >> 6;
    const int wt   = blockIdx.x & 63;
    const int lane = t & 63;
    const int lr   = lane & 15;
    const int lq   = lane >> 4;
    const int wave = t >> 6;

    if (t < KW * WT) {
        int k  = t >> 6;
        int wl = t & 63;
        int wg = wt * WT + wl;
        float p  = (float)(wg - 1 + k) + off[b * (KW * WLEN) + k * WLEN + wg];
        float m  = msk[b * (KW * WLEN) + k * WLEN + wg];
        float pf = floorf(p);
        float w1 = p - pf;
        float w0 = 1.0f - w1;
        int i0 = (int)pf;
        int i1 = i0 + 1;
        bool v0 = (i0 >= 0) & (i0 < WLEN);
        bool v1 = (i1 >= 0) & (i1 < WLEN);
        pi0[t] = min(max(i0, 0), WLEN - 1);
        pi1[t] = min(max(i1, 0), WLEN - 1);
        pw0[t] = v0 ? m * w0 : 0.0f;
        pw1[t] = v1 ? m * w1 : 0.0f;
    }
    __syncthreads();

    f32x4 acc[4][4];
#pragma unroll
    for (int i = 0; i < 4; ++i)
#pragma unroll
        for (int j = 0; j < 4; ++j)
            acc[i][j] = (f32x4){0.f, 0.f, 0.f, 0.f};

    const float* xb = x + (size_t)b * CCH * WLEN;

    for (int kc = 0; kc < CK; kc += 64) {
        {
            int cko  = (t & 7) * 8;
            int mrow = t >> 3;
#pragma unroll
            for (int r = 0; r < 8; ++r) {
                int m = mrow + r * 32;
                bf16x8 v = *reinterpret_cast<const bf16x8*>(wb + m * CK + kc + cko);
                *reinterpret_cast<bf16x8*>(&Wl[m * LDK + cko]) = v;
            }
        }
        {
            int wl  = t & 63;
            int ckg = t >> 6;
            short buf[16];
#pragma unroll
            for (int i = 0; i < 16; ++i) {
                int ck = kc + ckg * 16 + i;
                int c  = ck / 3;
                int k  = ck - 3 * c;
                int kwi = k * WT + wl;
                const float* xr = xb + c * WLEN;
                float s = pw0[kwi] * xr[pi0[kwi]] + pw1[kwi] * xr[pi1[kwi]];
                buf[i] = f2bf(s);
            }
            short* dst = &Sl[wl * LDK + ckg * 16];
            reinterpret_cast<bf16x8*>(dst)[0] = *reinterpret_cast<bf16x8*>(&buf[0]);
            reinterpret_cast<bf16x8*>(dst)[1] = *reinterpret_cast<bf16x8*>(&buf[8]);
        }
        __syncthreads();
        {
            int mbase = wave * 64;
#pragma unroll
            for (int ks = 0; ks < 2; ++ks) {
                int kk = ks * 32 + lq * 8;
                bf16x8 af[4], bfv[4];
#pragma unroll
                for (int mt = 0; mt < 4; ++mt)
                    af[mt] = *reinterpret_cast<const bf16x8*>(&Wl[(mbase + mt * 16 + lr) * LDK + kk]);
#pragma unroll
                for (int nt = 0; nt < 4; ++nt)
                    bfv[nt] = *reinterpret_cast<const bf16x8*>(&Sl[(nt * 16 + lr) * LDK + kk]);
#pragma unroll
                for (int mt = 0; mt < 4; ++mt)
#pragma unroll
                    for (int nt = 0; nt < 4; ++nt)
                        acc[mt][nt] = __builtin_amdgcn_mfma_f32_16x16x32_bf16(
                            af[mt], bfv[nt], acc[mt][nt], 0, 0, 0);
            }
        }
        __syncthreads();
    }

    {
        int mbase = wave * 64;
        float* ob = out + (size_t)b * OCH * WLEN + (size_t)wt * WT;
#pragma unroll
        for (int mt = 0; mt < 4; ++mt) {
#pragma unroll
            for (int r = 0; r < 4; ++r) {
                int oc = mbase + mt * 16 + lq * 4 + r;
                float bv = bias[oc];
                float* orow = ob + (size_t)oc * WLEN + lr;
#pragma unroll
                for (int nt = 0; nt < 4; ++nt)
                    orow[nt * 16] = acc[mt][nt][r] + bv;
            }
        }
    }
}

extern "C" void kernel_launch(void* const* d_in, const int* in_sizes, int n_in,
                              void* d_out, int out_size, void* d_ws, size_t ws_size,
                              hipStream_t stream) {
    const float* x    = (const float*)d_in[0];
    const float* w    = (const float*)d_in[1];
    const float* off  = (const float*)d_in[2];
    const float* msk  = (const float*)d_in[3];
    const float* bias = (const float*)d_in[4];
    float* out = (float*)d_out;
    short* wb  = (short*)d_ws;                       // 384 KB

    const size_t ST_OFF  = 512 * 1024;
    const size_t SBYTES  = (size_t)WLEN * CK * 2;    // 6 MB per batch
    size_t avail = (ws_size > ST_OFF) ? ws_size - ST_OFF : 0;
    int nb = (int)(avail / SBYTES);
    if (nb > BATCH) nb = BATCH;

    if (nb < 1) {
        wconv_kernel<<<768, 256, 0, stream>>>(w, wb);
        deform_mfma_kernel<<<BATCH * (WLEN / WT), 256, 0, stream>>>(x, wb, off, msk, bias, out);
        return;
    }

    short* St = (short*)((char*)d_ws + ST_OFF);
    for (int b0 = 0; b0 < BATCH; b0 += nb) {
        int n = (BATCH - b0 < nb) ? (BATCH - b0) : nb;
        sample_kernel<<<n * 256, 256, 0, stream>>>(x, w, wb, off, msk, St, b0);
        gemm_kernel<<<n * 64, 256, 0, stream>>>(wb, St, bias, out, b0);
    }
}

// Round 5
// 168.808 us; speedup vs baseline: 1.6615x; 1.1203x over previous
//
#include <hip/hip_runtime.h>

#define BATCH 16
#define CCH   256
#define WLEN  4096
#define OCH   256
#define KW    3
#define CK    768      // CCH*KW
#define WIN   96       // x-window floats per channel
#define SLD   200      // Sl row stride (shorts)

typedef short bf16x8 __attribute__((ext_vector_type(8)));
typedef float f32x4  __attribute__((ext_vector_type(4)));

__device__ inline short f2bf(float f) {
    union { float f; unsigned u; } v; v.f = f;
    unsigned r = v.u + 0x7FFFu + ((v.u >> 16) & 1u);   // RNE
    return (short)(r >> 16);
}

__device__ inline void gl_lds16(const void* g, void* l) {
    __builtin_amdgcn_global_load_lds(
        (const __attribute__((address_space(1))) unsigned int*)g,
        (__attribute__((address_space(3))) unsigned int*)l, 16, 0, 0);
}

// ---------------- kernel 1: weight fp32 [256][768] -> bf16 ----------------
__global__ void wconv_kernel(const float* __restrict__ w, short* __restrict__ wb) {
    int i = blockIdx.x * 256 + threadIdx.x;
    wb[i] = f2bf(w[i]);
}

// ---------------- fused kernel: gather windows -> LDS -> MFMA, no St ----------------
// grid: 16 b x 64 wt = 1024 blocks, 256 thr (4 waves). Per block: out[b, 0:256, wt*64:+64].
// K-loop: 4 chunks x 64 channels (192 ck). A-frags straight from global (L2-hot, 384 KB).
// Pipeline: window DMA for chunk c+1 issued before MFMA of chunk c.
__global__ __launch_bounds__(256)
void deform_fused_kernel(const float* __restrict__ x,
                         const short* __restrict__ wb,
                         const float* __restrict__ off,
                         const float* __restrict__ msk,
                         const float* __restrict__ bias,
                         float* __restrict__ out) {
    __shared__ float Win_s[4 * 16 * WIN];   // 24576 B: wave wv's 16 channels x 96 floats
    __shared__ short Sl[64 * SLD];          // 25600 B: gathered B-tile [w][192ck], padded

    const int t      = threadIdx.x;
    const int b      = blockIdx.x >> 6;
    const int wt     = blockIdx.x & 63;
    const int lane   = t & 63;
    const int wv     = t >> 6;
    const int lr     = lane & 15;
    const int lq     = lane >> 4;
    const int wstart = wt * 64 - 16;
    const int wg     = wt * 64 + lane;

    // ---- per-lane sampling params in registers (w = wg), dual-tap form ----
    int   li[3];
    float rw0[3], rw1[3];
#pragma unroll
    for (int k = 0; k < 3; ++k) {
        float o  = off[b * (KW * WLEN) + k * WLEN + wg];
        float m  = msk[b * (KW * WLEN) + k * WLEN + wg];
        float p  = (float)(wg - 1 + k) + o;
        float pf = floorf(p);
        float w1 = p - pf;
        int i0 = (int)pf;
        int i1 = i0 + 1;
        bool v0 = (i0 >= 0) & (i0 < WLEN);
        bool v1 = (i1 >= 0) & (i1 < WLEN);
        li[k]  = min(max(i0 - wstart, 0), WIN - 2);   // row[li], row[li+1] both in-window
        rw0[k] = v0 ? m * (1.0f - w1) : 0.0f;
        rw1[k] = v1 ? m * w1 : 0.0f;
    }

    const float* xb = x + (size_t)b * CCH * WLEN;
    float* const wbase = &Win_s[wv * 16 * WIN];

    f32x4 acc[4][4];
#pragma unroll
    for (int i = 0; i < 4; ++i)
#pragma unroll
        for (int j = 0; j < 4; ++j)
            acc[i][j] = (f32x4){0.f, 0.f, 0.f, 0.f};

    const int mbase = wv * 64;

    // ---- stage chunk c's windows: wave's 16 channels x 96 floats, 6x16B DMA/thread ----
    auto stage = [&](int c) {
        const int c0 = c * 64 + wv * 16;
#pragma unroll
        for (int it = 0; it < 6; ++it) {
            int i   = it * 64 + lane;
            int ch  = i / 24;                       // 24 float4-groups per channel
            int o16 = i - ch * 24;
            int j0  = min(max(wstart + o16 * 4, 0), WLEN - 4);
            gl_lds16(xb + (size_t)(c0 + ch) * WLEN + j0, wbase + it * 256);
        }
    };

    // ---- gather chunk from Win_s into Sl (B-tile layout [w][192]) ----
    auto gather = [&]() {
        short buf[48];
#pragma unroll
        for (int dc = 0; dc < 16; ++dc) {
            const float* row = wbase + dc * WIN;
#pragma unroll
            for (int k = 0; k < 3; ++k) {
                float v0 = row[li[k]];
                float v1 = row[li[k] + 1];
                buf[dc * 3 + k] = f2bf(rw0[k] * v0 + rw1[k] * v1);
            }
        }
#pragma unroll
        for (int j = 0; j < 6; ++j)
            *reinterpret_cast<bf16x8*>(&Sl[lane * SLD + wv * 48 + j * 8]) =
                *reinterpret_cast<bf16x8*>(&buf[j * 8]);
    };

    // ---- MFMA chunk c: A-frags from global (L2), B-frags from Sl ----
    auto mfma_chunk = [&](int c) {
#pragma unroll
        for (int ks = 0; ks < 6; ++ks) {
            bf16x8 af[4], bfv[4];
#pragma unroll
            for (int mt = 0; mt < 4; ++mt)
                af[mt] = *reinterpret_cast<const bf16x8*>(
                    wb + (size_t)(mbase + mt * 16 + lr) * CK + c * 192 + ks * 32 + lq * 8);
#pragma unroll
            for (int nt = 0; nt < 4; ++nt)
                bfv[nt] = *reinterpret_cast<const bf16x8*>(
                    &Sl[(nt * 16 + lr) * SLD + ks * 32 + lq * 8]);
#pragma unroll
            for (int mt = 0; mt < 4; ++mt)
#pragma unroll
                for (int nt = 0; nt < 4; ++nt)
                    acc[mt][nt] = __builtin_amdgcn_mfma_f32_16x16x32_bf16(
                        af[mt], bfv[nt], acc[mt][nt], 0, 0, 0);
        }
    };

    stage(0);
    __syncthreads();            // vmcnt drained by compiler before barrier
    gather();
    __syncthreads();
    for (int c = 0; c < 4; ++c) {
        if (c < 3) stage(c + 1);        // DMA in flight during MFMA
        mfma_chunk(c);
        __syncthreads();                // Sl reads done; windows arrived
        if (c < 3) {
            gather();
            __syncthreads();
        }
    }

    // ---- epilogue: D row = lq*4+reg (oc), col = lr (w) ----
    float* ob = out + ((size_t)b * OCH) * WLEN + wt * 64;
#pragma unroll
    for (int mt = 0; mt < 4; ++mt) {
#pragma unroll
        for (int r = 0; r < 4; ++r) {
            int row = mbase + mt * 16 + lq * 4 + r;
            float bv = bias[row];
            float* orow = ob + (size_t)row * WLEN + lr;
#pragma unroll
            for (int nt = 0; nt < 4; ++nt)
                orow[nt * 16] = acc[mt][nt][r] + bv;
        }
    }
}

extern "C" void kernel_launch(void* const* d_in, const int* in_sizes, int n_in,
                              void* d_out, int out_size, void* d_ws, size_t ws_size,
                              hipStream_t stream) {
    const float* x    = (const float*)d_in[0];
    const float* w    = (const float*)d_in[1];
    const float* off  = (const float*)d_in[2];
    const float* msk  = (const float*)d_in[3];
    const float* bias = (const float*)d_in[4];
    float* out = (float*)d_out;
    short* wb  = (short*)d_ws;   // 384 KB bf16 weights

    wconv_kernel<<<768, 256, 0, stream>>>(w, wb);
    deform_fused_kernel<<<BATCH * 64, 256, 0, stream>>>(x, wb, off, msk, bias, out);
}